// Round 7
// baseline (330.913 us; speedup 1.0000x reference)
//
#include <hip/hip_runtime.h>
#include <stdint.h>

#define M_DIM 1024
#define K_DIM 4096
#define N_DIM 11008
#define NPACK 1376
#define NGROUPS 32

#define BM 256
#define BN 256
#define BK 64
#define NT (K_DIM / BK)     // 64
#define ATILE (BM * BK)
#define BTILE (BN * BK)

typedef __attribute__((ext_vector_type(4))) float f32x4;
typedef __attribute__((ext_vector_type(8))) _Float16 f16x8;
typedef __attribute__((ext_vector_type(2))) _Float16 h2;

static __device__ __forceinline__ unsigned int swz(unsigned int r) {
  return (r ^ (r >> 3)) & 7u;
}

// prepass: x fp32 -> fp16 (exact: x was originally fp16)
__global__ __launch_bounds__(256)
void conv_x(const float* __restrict__ X, unsigned short* __restrict__ XH) {
  const size_t i = ((size_t)blockIdx.x * 256 + threadIdx.x) * 8;
  const float4 a = *(const float4*)(X + i);
  const float4 b = *(const float4*)(X + i + 4);
  uint4 o;
  o.x = __builtin_bit_cast(unsigned int, __builtin_amdgcn_cvt_pkrtz(a.x, a.y));
  o.y = __builtin_bit_cast(unsigned int, __builtin_amdgcn_cvt_pkrtz(a.z, a.w));
  o.z = __builtin_bit_cast(unsigned int, __builtin_amdgcn_cvt_pkrtz(b.x, b.y));
  o.w = __builtin_bit_cast(unsigned int, __builtin_amdgcn_cvt_pkrtz(b.z, b.w));
  *(uint4*)(XH + i) = o;
}

// V=0: real kernel (round-5 structure, best so far: 160us)
// V=1: no dequant/ds_write/qw/scale loads  (A-staging + ds_read + MFMA)
// V=2: no staging at all                   (ds_read + MFMA + barriers only)
// Probes (V!=0) write NOTHING; results kept live via asm (rule #17).
template <int V>
__global__ __launch_bounds__(512, 2)
void awq_probe(const unsigned short* __restrict__ XH,
               const int* __restrict__ QW,
               const int* __restrict__ QZ,
               const float* __restrict__ S,
               const float* __restrict__ BIAS,
               float* __restrict__ OUT)
{
  __shared__ unsigned short Alds[2][ATILE];
  __shared__ unsigned short Blds[2][BTILE];

  const int tid  = threadIdx.x;
  const int lane = tid & 63;
  const int wid  = tid >> 6;
  const int wr   = wid >> 2;
  const int wc   = wid & 3;
  const int l15  = lane & 15;
  const int l4   = lane >> 4;

  const int row0 = blockIdx.y * BM;
  const int n0   = blockIdx.x * BN;
  const int p0   = n0 >> 3;

  const int dq_p = tid & 31;
  const int dq_k = (tid >> 5) << 2;

  f32x4 acc[8][4];
  #pragma unroll
  for (int i = 0; i < 8; ++i)
    #pragma unroll
    for (int j = 0; j < 4; ++j)
      acc[i][j] = (f32x4){0.f, 0.f, 0.f, 0.f};

  const int SH[8] = {0, 16, 4, 20, 8, 24, 12, 28};
  unsigned int zz[8], ss[8];

  auto stageA = [&](int buf, int k0) {
    #pragma unroll
    for (int i = 0; i < 4; ++i) {
      const int gb = i * 512 + wid * 64;
      const int g  = gb + lane;
      const unsigned int r = (unsigned)(g >> 3), c = (unsigned)(g & 7);
      const unsigned short* gsrc =
          XH + (size_t)(row0 + r) * K_DIM + k0 + ((c ^ swz(r)) << 3);
      __builtin_amdgcn_global_load_lds(
          (const __attribute__((address_space(1))) void*)gsrc,
          (__attribute__((address_space(3))) void*)(&Alds[buf][gb * 8]),
          16, 0, 0);
    }
  };

  auto prepGroup = [&](int grp) {
    const unsigned int qzv = (unsigned int)QZ[grp * NPACK + p0 + dq_p];
    const float* sp = S + (size_t)grp * N_DIM + n0 + dq_p * 8;
    const float4 sv0 = *(const float4*)sp;
    const float4 sv1 = *(const float4*)(sp + 4);
    const float svf[8] = {sv0.x, sv0.y, sv0.z, sv0.w, sv1.x, sv1.y, sv1.z, sv1.w};
    #pragma unroll
    for (int j = 0; j < 8; ++j) {
      const unsigned int z = (qzv >> SH[j]) & 15u;
      zz[j] = z * 0x10001u + 0x64006400u;
      ss[j] = __builtin_bit_cast(unsigned int, __builtin_amdgcn_cvt_pkrtz(svf[j], svf[j]));
    }
  };

  unsigned int qwc[4], qwn[4];
  auto loadQW = [&](unsigned int* dst, int k0) {
    #pragma unroll
    for (int i = 0; i < 4; ++i)
      dst[i] = (unsigned int)QW[(size_t)(k0 + dq_k + i) * NPACK + p0 + dq_p];
  };

  auto dequantWriteB = [&](int buf, const unsigned int* qw) {
    #pragma unroll
    for (int j = 0; j < 8; ++j) {
      const int sh = SH[j];
      const unsigned int q01 =
          ((qw[0] >> sh) & 15u) | (((qw[1] >> sh) & 15u) << 16) | 0x64006400u;
      const unsigned int q23 =
          ((qw[2] >> sh) & 15u) | (((qw[3] >> sh) & 15u) << 16) | 0x64006400u;
      const h2 w01 = (__builtin_bit_cast(h2, q01) - __builtin_bit_cast(h2, zz[j])) *
                     __builtin_bit_cast(h2, ss[j]);
      const h2 w23 = (__builtin_bit_cast(h2, q23) - __builtin_bit_cast(h2, zz[j])) *
                     __builtin_bit_cast(h2, ss[j]);
      uint2 wb;
      wb.x = __builtin_bit_cast(unsigned int, w01);
      wb.y = __builtin_bit_cast(unsigned int, w23);
      const unsigned int nn = dq_p * 8 + j;
      *(uint2*)((char*)&Blds[buf][0] + nn * 128 + ((dq_k * 2) ^ (swz(nn) << 4))) = wb;
    }
  };

  // ---------------- prologue ----------------
  if constexpr (V != 2) stageA(0, 0);
  if constexpr (V == 0) {
    prepGroup(0);
    loadQW(qwc, 0);
    dequantWriteB(0, qwc);
    loadQW(qwn, BK);
  }
  __syncthreads();

  int cur = 0;
  for (int t = 0; t < NT; ++t) {
    if (t + 1 < NT) {
      const int kn = (t + 1) * BK;
      if constexpr (V != 2) stageA(cur ^ 1, kn);
      if constexpr (V == 0) {
        if (((t + 1) & 1) == 0) prepGroup((t + 1) >> 1);
        dequantWriteB(cur ^ 1, qwn);
        if (t + 2 < NT) loadQW(qwn, kn + BK);
      }
    }

    const char* Ac = (const char*)&Alds[cur][0];
    const char* Bc = (const char*)&Blds[cur][0];
    #pragma unroll
    for (int kk = 0; kk < 2; ++kk) {
      f16x8 afv[8], bfv[4];
      #pragma unroll
      for (int m = 0; m < 8; ++m) {
        const unsigned int r = (unsigned)(wr * 128 + m * 16 + l15);
        afv[m] = *(const f16x8*)(Ac + r * 128 + (((unsigned)(kk * 4 + l4) ^ swz(r)) << 4));
      }
      #pragma unroll
      for (int n = 0; n < 4; ++n) {
        const unsigned int r = (unsigned)(wc * 64 + n * 16 + l15);
        bfv[n] = *(const f16x8*)(Bc + r * 128 + (((unsigned)(kk * 4 + l4) ^ swz(r)) << 4));
      }
      #pragma unroll
      for (int m = 0; m < 8; ++m)
        #pragma unroll
        for (int n = 0; n < 4; ++n)
          acc[m][n] = __builtin_amdgcn_mfma_f32_16x16x32_f16(afv[m], bfv[n], acc[m][n], 0, 0, 0);
    }

    __syncthreads();
    cur ^= 1;
  }

  // ---------------- epilogue ----------------
  if constexpr (V == 0) {
    #pragma unroll
    for (int n = 0; n < 4; ++n) {
      const int col = n0 + wc * 64 + n * 16 + l15;
      const float bz = BIAS[col];
      #pragma unroll
      for (int m = 0; m < 8; ++m) {
        const int rbase = row0 + wr * 128 + m * 16 + l4 * 4;
        #pragma unroll
        for (int r = 0; r < 4; ++r) {
          OUT[(size_t)(rbase + r) * N_DIM + col] = acc[m][n][r] + bz;
        }
      }
    }
  } else {
    // keep all MFMA results live without any store (rule #17)
    float sink = 0.f;
    #pragma unroll
    for (int m = 0; m < 8; ++m)
      #pragma unroll
      for (int n = 0; n < 4; ++n)
        sink += acc[m][n][0] + acc[m][n][1] + acc[m][n][2] + acc[m][n][3];
    asm volatile("" :: "v"(sink));
  }
}

// ---------------- fallback (fp32 x, no workspace) ----------------
__global__ __launch_bounds__(512, 2)
void awq_gemm_fb(const float* __restrict__ XF,
                 const int* __restrict__ QW,
                 const int* __restrict__ QZ,
                 const float* __restrict__ S,
                 const float* __restrict__ BIAS,
                 float* __restrict__ OUT)
{
  __shared__ unsigned short Alds[2][ATILE];
  __shared__ unsigned short Blds[2][BTILE];

  const int tid  = threadIdx.x;
  const int lane = tid & 63;
  const int wid  = tid >> 6;
  const int wr   = wid >> 2;
  const int wc   = wid & 3;
  const int l15  = lane & 15;
  const int l4   = lane >> 4;

  const int row0 = blockIdx.y * BM;
  const int n0   = blockIdx.x * BN;
  const int p0   = n0 >> 3;

  const int dq_p = tid & 31;
  const int dq_k = (tid >> 5) << 2;

  f32x4 acc[8][4];
  #pragma unroll
  for (int i = 0; i < 8; ++i)
    #pragma unroll
    for (int j = 0; j < 4; ++j)
      acc[i][j] = (f32x4){0.f, 0.f, 0.f, 0.f};

  const int SH[8] = {0, 16, 4, 20, 8, 24, 12, 28};
  unsigned int zz[8], ss[8];

  auto stageA = [&](int buf, int k0) {
    #pragma unroll
    for (int i = 0; i < 4; ++i) {
      const int g = i * 512 + tid;
      const unsigned int r = (unsigned)(g >> 3), c = (unsigned)(g & 7);
      const float* src = XF + (size_t)(row0 + r) * K_DIM + k0 + (c << 3);
      const float4 v0 = *(const float4*)src;
      const float4 v1 = *(const float4*)(src + 4);
      uint4 o;
      o.x = __builtin_bit_cast(unsigned int, __builtin_amdgcn_cvt_pkrtz(v0.x, v0.y));
      o.y = __builtin_bit_cast(unsigned int, __builtin_amdgcn_cvt_pkrtz(v0.z, v0.w));
      o.z = __builtin_bit_cast(unsigned int, __builtin_amdgcn_cvt_pkrtz(v1.x, v1.y));
      o.w = __builtin_bit_cast(unsigned int, __builtin_amdgcn_cvt_pkrtz(v1.z, v1.w));
      *(uint4*)((char*)&Alds[buf][0] + r * 128 + ((c ^ swz(r)) << 4)) = o;
    }
  };

  auto prepGroup = [&](int grp) {
    const unsigned int qzv = (unsigned int)QZ[grp * NPACK + p0 + dq_p];
    const float* sp = S + (size_t)grp * N_DIM + n0 + dq_p * 8;
    const float4 sv0 = *(const float4*)sp;
    const float4 sv1 = *(const float4*)(sp + 4);
    const float svf[8] = {sv0.x, sv0.y, sv0.z, sv0.w, sv1.x, sv1.y, sv1.z, sv1.w};
    #pragma unroll
    for (int j = 0; j < 8; ++j) {
      const unsigned int z = (qzv >> SH[j]) & 15u;
      zz[j] = z * 0x10001u + 0x64006400u;
      ss[j] = __builtin_bit_cast(unsigned int, __builtin_amdgcn_cvt_pkrtz(svf[j], svf[j]));
    }
  };

  unsigned int qwc[4], qwn[4];
  auto loadQW = [&](unsigned int* dst, int k0) {
    #pragma unroll
    for (int i = 0; i < 4; ++i)
      dst[i] = (unsigned int)QW[(size_t)(k0 + dq_k + i) * NPACK + p0 + dq_p];
  };

  auto dequantWriteB = [&](int buf, const unsigned int* qw) {
    #pragma unroll
    for (int j = 0; j < 8; ++j) {
      const int sh = SH[j];
      const unsigned int q01 =
          ((qw[0] >> sh) & 15u) | (((qw[1] >> sh) & 15u) << 16) | 0x64006400u;
      const unsigned int q23 =
          ((qw[2] >> sh) & 15u) | (((qw[3] >> sh) & 15u) << 16) | 0x64006400u;
      const h2 w01 = (__builtin_bit_cast(h2, q01) - __builtin_bit_cast(h2, zz[j])) *
                     __builtin_bit_cast(h2, ss[j]);
      const h2 w23 = (__builtin_bit_cast(h2, q23) - __builtin_bit_cast(h2, zz[j])) *
                     __builtin_bit_cast(h2, ss[j]);
      uint2 wb;
      wb.x = __builtin_bit_cast(unsigned int, w01);
      wb.y = __builtin_bit_cast(unsigned int, w23);
      const unsigned int nn = dq_p * 8 + j;
      *(uint2*)((char*)&Blds[buf][0] + nn * 128 + ((dq_k * 2) ^ (swz(nn) << 4))) = wb;
    }
  };

  stageA(0, 0);
  prepGroup(0);
  loadQW(qwc, 0);
  dequantWriteB(0, qwc);
  loadQW(qwn, BK);
  __syncthreads();

  int cur = 0;
  for (int t = 0; t < NT; ++t) {
    if (t + 1 < NT) {
      const int kn = (t + 1) * BK;
      stageA(cur ^ 1, kn);
      if (((t + 1) & 1) == 0) prepGroup((t + 1) >> 1);
      dequantWriteB(cur ^ 1, qwn);
      if (t + 2 < NT) loadQW(qwn, kn + BK);
    }
    const char* Ac = (const char*)&Alds[cur][0];
    const char* Bc = (const char*)&Blds[cur][0];
    #pragma unroll
    for (int kk = 0; kk < 2; ++kk) {
      f16x8 afv[8], bfv[4];
      #pragma unroll
      for (int m = 0; m < 8; ++m) {
        const unsigned int r = (unsigned)(wr * 128 + m * 16 + l15);
        afv[m] = *(const f16x8*)(Ac + r * 128 + (((unsigned)(kk * 4 + l4) ^ swz(r)) << 4));
      }
      #pragma unroll
      for (int n = 0; n < 4; ++n) {
        const unsigned int r = (unsigned)(wc * 64 + n * 16 + l15);
        bfv[n] = *(const f16x8*)(Bc + r * 128 + (((unsigned)(kk * 4 + l4) ^ swz(r)) << 4));
      }
      #pragma unroll
      for (int m = 0; m < 8; ++m)
        #pragma unroll
        for (int n = 0; n < 4; ++n)
          acc[m][n] = __builtin_amdgcn_mfma_f32_16x16x32_f16(afv[m], bfv[n], acc[m][n], 0, 0, 0);
    }
    __syncthreads();
    cur ^= 1;
  }

  #pragma unroll
  for (int n = 0; n < 4; ++n) {
    const int col = n0 + wc * 64 + n * 16 + l15;
    const float bz = BIAS[col];
    #pragma unroll
    for (int m = 0; m < 8; ++m) {
      const int rbase = row0 + wr * 128 + m * 16 + l4 * 4;
      #pragma unroll
      for (int r = 0; r < 4; ++r) {
        OUT[(size_t)(rbase + r) * N_DIM + col] = acc[m][n][r] + bz;
      }
    }
  }
}

extern "C" void kernel_launch(void* const* d_in, const int* in_sizes, int n_in,
                              void* d_out, int out_size, void* d_ws, size_t ws_size,
                              hipStream_t stream) {
  const float* x = nullptr; const int* qw = nullptr; const int* qz = nullptr;
  const float* s = nullptr; const float* b = nullptr;
  for (int i = 0; i < n_in; ++i) {
    switch (in_sizes[i]) {
      case M_DIM * K_DIM:   x  = (const float*)d_in[i]; break;
      case K_DIM * NPACK:   qw = (const int*)d_in[i];   break;
      case NGROUPS * NPACK: qz = (const int*)d_in[i];   break;
      case NGROUPS * N_DIM: s  = (const float*)d_in[i]; break;
      case N_DIM:           b  = (const float*)d_in[i]; break;
    }
  }
  float* out = (float*)d_out;

  dim3 grid(N_DIM / BN, M_DIM / BM);  // 43 x 4 = 172
  const size_t xh_bytes = (size_t)M_DIM * K_DIM * 2;
  if (ws_size >= xh_bytes) {
    unsigned short* xh = (unsigned short*)d_ws;
    conv_x<<<(M_DIM * K_DIM) / (256 * 8), 256, 0, stream>>>(x, xh);
    // V0: real output
    awq_probe<0><<<grid, dim3(512), 0, stream>>>(xh, qw, qz, s, b, out);
    // diagnostics (no stores; asm-live): V1 = no dequant path; V2 = no staging
    awq_probe<1><<<grid, dim3(512), 0, stream>>>(xh, qw, qz, s, b, out);
    awq_probe<2><<<grid, dim3(512), 0, stream>>>(xh, qw, qz, s, b, out);
  } else {
    awq_gemm_fb<<<grid, dim3(512), 0, stream>>>(x, qw, qz, s, b, out);
  }
}

// Round 8
// 179.032 us; speedup vs baseline: 1.8483x; 1.8483x over previous
//
#include <hip/hip_runtime.h>
#include <stdint.h>

#define M_DIM 1024
#define K_DIM 4096
#define N_DIM 11008
#define NPACK 1376
#define NGROUPS 32
#define K8 (K_DIM / 8)      // 512

#define BM 128
#define BN 128
#define BK 64
#define NT (K_DIM / BK)     // 64
#define ATILE (BM * BK)     // 8192 shorts = 16 KiB

typedef __attribute__((ext_vector_type(4))) float f32x4;
typedef __attribute__((ext_vector_type(8))) _Float16 f16x8;
typedef __attribute__((ext_vector_type(2))) _Float16 h2;

static __device__ __forceinline__ unsigned swz(unsigned r) {
  return (r ^ (r >> 3)) & 7u;
}

// ---------- prepass 1: x fp32 -> fp16 (exact; x was originally fp16) ----------
__global__ __launch_bounds__(256)
void conv_x(const float* __restrict__ X, unsigned short* __restrict__ XH) {
  const size_t i = ((size_t)blockIdx.x * 256 + threadIdx.x) * 8;
  const float4 a = *(const float4*)(X + i);
  const float4 b = *(const float4*)(X + i + 4);
  uint4 o;
  o.x = __builtin_bit_cast(unsigned, __builtin_amdgcn_cvt_pkrtz(a.x, a.y));
  o.y = __builtin_bit_cast(unsigned, __builtin_amdgcn_cvt_pkrtz(a.z, a.w));
  o.z = __builtin_bit_cast(unsigned, __builtin_amdgcn_cvt_pkrtz(b.x, b.y));
  o.w = __builtin_bit_cast(unsigned, __builtin_amdgcn_cvt_pkrtz(b.z, b.w));
  *(uint4*)(XH + i) = o;
}

// ---------- prepass 2: repack qweight nibbles K-major per column ----------
// out: QWR[k8][n] dword = nibbles for k = 8*k8..8*k8+7 of column n (nibble i = k8*8+i)
// 8x8 nibble transpose (delta-swap network) + AWQ reverse-order folded into store.
__global__ __launch_bounds__(256)
void repack_qw(const int* __restrict__ QW, unsigned* __restrict__ QWR) {
  const int idx = blockIdx.x * 256 + threadIdx.x;   // exactly NPACK*K8 threads
  const int p  = idx % NPACK;
  const int k8 = idx / NPACK;
  unsigned a[8];
  #pragma unroll
  for (int i = 0; i < 8; ++i)
    a[i] = (unsigned)QW[(size_t)(k8 * 8 + i) * NPACK + p];
  // step d=1: swap odd-nibbles of a[i] with even-nibbles of a[i+1]
  #pragma unroll
  for (int i = 0; i < 8; i += 2) {
    unsigned t = ((a[i] >> 4) ^ a[i + 1]) & 0x0F0F0F0Fu;
    a[i + 1] ^= t;  a[i] ^= t << 4;
  }
  // step d=2 (2-nibble cells)
  #pragma unroll
  for (int g = 0; g < 8; g += 4)
    #pragma unroll
    for (int i = 0; i < 2; ++i) {
      unsigned t = ((a[g + i] >> 8) ^ a[g + i + 2]) & 0x00FF00FFu;
      a[g + i + 2] ^= t;  a[g + i] ^= t << 8;
    }
  // step d=4 (4-nibble cells)
  #pragma unroll
  for (int i = 0; i < 4; ++i) {
    unsigned t = ((a[i] >> 16) ^ a[i + 4]) & 0x0000FFFFu;
    a[i + 4] ^= t;  a[i] ^= t << 16;
  }
  // now a[s].nibble[i] = orig a[i].nibble[s]; column n=8p+j uses source nibble rev[j]
  const int REV[8] = {0, 4, 1, 5, 2, 6, 3, 7};
  #pragma unroll
  for (int j = 0; j < 8; ++j)
    QWR[(size_t)k8 * N_DIM + 8 * p + j] = a[REV[j]];
}

// ---------- main GEMM: A via LDS (dbuf, swizzled), B dequant in registers ----------
template <bool PREX>
__global__ __launch_bounds__(256, 3)
void awq_gemm_rb(const unsigned short* __restrict__ XH,
                 const float* __restrict__ XF,
                 const unsigned* __restrict__ QWR,
                 const int* __restrict__ QZ,
                 const float* __restrict__ S,
                 const float* __restrict__ BIAS,
                 float* __restrict__ OUT)
{
  __shared__ unsigned short Alds[2][ATILE];   // 2 x 16 KiB

  const int tid  = threadIdx.x;
  const int lane = tid & 63;
  const int wid  = tid >> 6;      // 0..3
  const int wr   = wid >> 1;      // 2 wave rows
  const int wc   = wid & 1;       // 2 wave cols
  const int l15  = lane & 15;
  const int l4   = lane >> 4;

  const int row0 = blockIdx.y * BM;
  const int n0   = blockIdx.x * BN;
  const int ncol = n0 + wc * 64 + l15;          // lane's base output column

  // zero-nibble shift for this lane's columns: j=n&7=l15&7, rev[j]=(j>>1)|((j&1)<<2)
  const int jz   = l15 & 7;
  const int sh_z = (((jz >> 1) | ((jz & 1) << 2)) << 2);

  f32x4 acc[4][4];
  #pragma unroll
  for (int i = 0; i < 4; ++i)
    #pragma unroll
    for (int j = 0; j < 4; ++j)
      acc[i][j] = (f32x4){0.f, 0.f, 0.f, 0.f};

  unsigned zz[4], ss[4];        // group constants (packed fp16)
  unsigned qn[4]; float sn[4];  // next-group staging

  auto prepLoad = [&](int grp) {
    #pragma unroll
    for (int nf = 0; nf < 4; ++nf) {
      const int n = ncol + nf * 16;
      qn[nf] = (unsigned)QZ[grp * NPACK + (n >> 3)];
      sn[nf] = S[(size_t)grp * N_DIM + n];
    }
  };
  auto prepCalc = [&]() {
    #pragma unroll
    for (int nf = 0; nf < 4; ++nf) {
      const unsigned z = (qn[nf] >> sh_z) & 15u;
      zz[nf] = z * 0x10001u + 0x64006400u;
      ss[nf] = __builtin_bit_cast(unsigned, __builtin_amdgcn_cvt_pkrtz(sn[nf], sn[nf]));
    }
  };

  auto stageA = [&](unsigned short* dst, int k0) {
    if constexpr (PREX) {
      #pragma unroll
      for (int i = 0; i < 4; ++i) {
        const int gb = i * 256 + wid * 64;       // wave-uniform granule base
        const int g  = gb + lane;
        const unsigned r = (unsigned)(g >> 3), c = (unsigned)(g & 7);
        const unsigned short* gsrc =
            XH + (size_t)(row0 + r) * K_DIM + k0 + ((c ^ swz(r)) << 3);
        __builtin_amdgcn_global_load_lds(
            (const __attribute__((address_space(1))) void*)gsrc,
            (__attribute__((address_space(3))) void*)(dst + gb * 8), 16, 0, 0);
      }
    } else {
      #pragma unroll
      for (int i = 0; i < 4; ++i) {
        const int g = i * 256 + tid;
        const unsigned r = (unsigned)(g >> 3), c = (unsigned)(g & 7);
        const float* src = XF + (size_t)(row0 + r) * K_DIM + k0 + (c << 3);
        const float4 v0 = *(const float4*)src;
        const float4 v1 = *(const float4*)(src + 4);
        uint4 o;
        o.x = __builtin_bit_cast(unsigned, __builtin_amdgcn_cvt_pkrtz(v0.x, v0.y));
        o.y = __builtin_bit_cast(unsigned, __builtin_amdgcn_cvt_pkrtz(v0.z, v0.w));
        o.z = __builtin_bit_cast(unsigned, __builtin_amdgcn_cvt_pkrtz(v1.x, v1.y));
        o.w = __builtin_bit_cast(unsigned, __builtin_amdgcn_cvt_pkrtz(v1.z, v1.w));
        *(uint4*)((char*)dst + r * 128 + ((c ^ swz(r)) << 4)) = o;
      }
    }
  };

  auto loadB = [&](unsigned* dst, int t) {
    const unsigned* bp = QWR + (size_t)(t * 8 + l4) * N_DIM + ncol;
    #pragma unroll
    for (int kk = 0; kk < 2; ++kk)
      #pragma unroll
      for (int nf = 0; nf < 4; ++nf)
        dst[kk * 4 + nf] = bp[(size_t)(kk * 4) * N_DIM + nf * 16];
  };

  auto compute = [&](const unsigned short* Ab, const unsigned* breg) {
    #pragma unroll
    for (int kk = 0; kk < 2; ++kk) {
      f16x8 af[4];
      #pragma unroll
      for (int m = 0; m < 4; ++m) {
        const unsigned r = (unsigned)(wr * 64 + m * 16 + l15);
        af[m] = *(const f16x8*)((const char*)Ab + r * 128 +
                                (((unsigned)(kk * 4 + l4) ^ swz(r)) << 4));
      }
      #pragma unroll
      for (int nf = 0; nf < 4; ++nf) {
        const unsigned w = breg[kk * 4 + nf];
        const unsigned e = w & 0x0F0F0F0Fu;
        const unsigned o = (w >> 4) & 0x0F0F0F0Fu;
        union { unsigned u[4]; f16x8 v; } bf;
        #pragma unroll
        for (int q = 0; q < 4; ++q) {
          // bytes: [e.b[q], 0, o.b[q], 0] -> +0x6400 halves = (1024+k_even, 1024+k_odd)
          const unsigned sel = 0x0C000C00u | (unsigned)q | ((unsigned)(4 + q) << 16);
          const unsigned hv  = __builtin_amdgcn_perm(o, e, sel) | 0x64006400u;
          const h2 wv = (__builtin_bit_cast(h2, hv) - __builtin_bit_cast(h2, zz[nf])) *
                        __builtin_bit_cast(h2, ss[nf]);
          bf.u[q] = __builtin_bit_cast(unsigned, wv);
        }
        #pragma unroll
        for (int m = 0; m < 4; ++m)
          acc[m][nf] = __builtin_amdgcn_mfma_f32_16x16x32_f16(af[m], bf.v, acc[m][nf], 0, 0, 0);
      }
    }
  };

  unsigned bE[8], bO[8];

  // ---------------- prologue ----------------
  prepLoad(0); prepCalc();
  stageA(&Alds[0][0], 0);
  loadB(bE, 0);
  __syncthreads();                 // A0 ready (compiler drains vmcnt before barrier)

  // ---------------- main loop: 32 iters x 2 tiles ----------------
  for (int I = 0; I < 32; ++I) {
    // EVEN tile 2I: compute(A0,bE); stage A1 <- 2I+1; load bO <- 2I+1
    stageA(&Alds[1][0], (2 * I + 1) * BK);
    loadB(bO, 2 * I + 1);
    compute(&Alds[0][0], bE);
    __syncthreads();
    // ODD tile 2I+1: compute(A1,bO); stage A0 <- 2I+2; load bE; prep group I+1
    if (I < 31) {
      stageA(&Alds[0][0], (2 * I + 2) * BK);
      loadB(bE, 2 * I + 2);
      prepLoad(I + 1);
    }
    compute(&Alds[1][0], bO);     // uses group-I constants
    if (I < 31) prepCalc();       // switch zz/ss to group I+1
    __syncthreads();
  }

  // ---------------- epilogue: + bias, store fp32 ----------------
  // C/D layout (m89, dtype-independent): col = lane&15, row = (lane>>4)*4 + reg
  #pragma unroll
  for (int nf = 0; nf < 4; ++nf) {
    const int col = ncol + nf * 16;
    const float bz = BIAS[col];
    #pragma unroll
    for (int m = 0; m < 4; ++m) {
      const int rbase = row0 + wr * 64 + m * 16 + l4 * 4;
      #pragma unroll
      for (int r = 0; r < 4; ++r)
        OUT[(size_t)(rbase + r) * N_DIM + col] = acc[m][nf][r] + bz;
    }
  }
}

// ---------------- fallback (round-5 structure, fp32 x, minimal ws) ----------------
__global__ __launch_bounds__(512, 2)
void awq_gemm_fb(const float* __restrict__ XF,
                 const int* __restrict__ QW,
                 const int* __restrict__ QZ,
                 const float* __restrict__ S,
                 const float* __restrict__ BIAS,
                 float* __restrict__ OUT)
{
  __shared__ unsigned short Al[2][256 * 64];
  __shared__ unsigned short Bl[2][256 * 64];

  const int tid = threadIdx.x, lane = tid & 63, wid = tid >> 6;
  const int wr = wid >> 2, wc = wid & 3, l15 = lane & 15, l4 = lane >> 4;
  const int row0 = blockIdx.y * 256, n0 = blockIdx.x * 256, p0 = n0 >> 3;
  const int dq_p = tid & 31, dq_k = (tid >> 5) << 2;

  f32x4 acc[8][4];
  #pragma unroll
  for (int i = 0; i < 8; ++i)
    #pragma unroll
    for (int j = 0; j < 4; ++j) acc[i][j] = (f32x4){0.f, 0.f, 0.f, 0.f};

  const int SH[8] = {0, 16, 4, 20, 8, 24, 12, 28};
  unsigned zz[8], ssv[8];

  auto stageA = [&](int buf, int k0) {
    #pragma unroll
    for (int i = 0; i < 4; ++i) {
      const int g = i * 512 + tid;
      const unsigned r = (unsigned)(g >> 3), c = (unsigned)(g & 7);
      const float* src = XF + (size_t)(row0 + r) * K_DIM + k0 + (c << 3);
      const float4 v0 = *(const float4*)src;
      const float4 v1 = *(const float4*)(src + 4);
      uint4 o;
      o.x = __builtin_bit_cast(unsigned, __builtin_amdgcn_cvt_pkrtz(v0.x, v0.y));
      o.y = __builtin_bit_cast(unsigned, __builtin_amdgcn_cvt_pkrtz(v0.z, v0.w));
      o.z = __builtin_bit_cast(unsigned, __builtin_amdgcn_cvt_pkrtz(v1.x, v1.y));
      o.w = __builtin_bit_cast(unsigned, __builtin_amdgcn_cvt_pkrtz(v1.z, v1.w));
      *(uint4*)((char*)&Al[buf][0] + r * 128 + ((c ^ swz(r)) << 4)) = o;
    }
  };
  auto prepGroup = [&](int grp) {
    const unsigned qzv = (unsigned)QZ[grp * NPACK + p0 + dq_p];
    const float* sp = S + (size_t)grp * N_DIM + n0 + dq_p * 8;
    const float4 sv0 = *(const float4*)sp;
    const float4 sv1 = *(const float4*)(sp + 4);
    const float svf[8] = {sv0.x, sv0.y, sv0.z, sv0.w, sv1.x, sv1.y, sv1.z, sv1.w};
    #pragma unroll
    for (int j = 0; j < 8; ++j) {
      const unsigned z = (qzv >> SH[j]) & 15u;
      zz[j] = z * 0x10001u + 0x64006400u;
      ssv[j] = __builtin_bit_cast(unsigned, __builtin_amdgcn_cvt_pkrtz(svf[j], svf[j]));
    }
  };
  unsigned qwc[4], qwn[4];
  auto loadQW = [&](unsigned* dst, int k0) {
    #pragma unroll
    for (int i = 0; i < 4; ++i)
      dst[i] = (unsigned)QW[(size_t)(k0 + dq_k + i) * NPACK + p0 + dq_p];
  };
  auto deqB = [&](int buf, const unsigned* qw) {
    #pragma unroll
    for (int j = 0; j < 8; ++j) {
      const int sh = SH[j];
      const unsigned q01 = ((qw[0] >> sh) & 15u) | (((qw[1] >> sh) & 15u) << 16) | 0x64006400u;
      const unsigned q23 = ((qw[2] >> sh) & 15u) | (((qw[3] >> sh) & 15u) << 16) | 0x64006400u;
      const h2 w01 = (__builtin_bit_cast(h2, q01) - __builtin_bit_cast(h2, zz[j])) *
                     __builtin_bit_cast(h2, ssv[j]);
      const h2 w23 = (__builtin_bit_cast(h2, q23) - __builtin_bit_cast(h2, zz[j])) *
                     __builtin_bit_cast(h2, ssv[j]);
      uint2 wb;
      wb.x = __builtin_bit_cast(unsigned, w01);
      wb.y = __builtin_bit_cast(unsigned, w23);
      const unsigned nn = dq_p * 8 + j;
      *(uint2*)((char*)&Bl[buf][0] + nn * 128 + ((dq_k * 2) ^ (swz(nn) << 4))) = wb;
    }
  };

  stageA(0, 0); prepGroup(0); loadQW(qwc, 0); deqB(0, qwc); loadQW(qwn, BK);
  __syncthreads();
  int cur = 0;
  for (int t = 0; t < NT; ++t) {
    if (t + 1 < NT) {
      const int kn = (t + 1) * BK;
      stageA(cur ^ 1, kn);
      if (((t + 1) & 1) == 0) prepGroup((t + 1) >> 1);
      deqB(cur ^ 1, qwn);
      if (t + 2 < NT) loadQW(qwn, kn + BK);
    }
    const char* Ac = (const char*)&Al[cur][0];
    const char* Bc = (const char*)&Bl[cur][0];
    #pragma unroll
    for (int kk = 0; kk < 2; ++kk) {
      f16x8 afv[8], bfv[4];
      #pragma unroll
      for (int m = 0; m < 8; ++m) {
        const unsigned r = (unsigned)(wr * 128 + m * 16 + l15);
        afv[m] = *(const f16x8*)(Ac + r * 128 + (((unsigned)(kk * 4 + l4) ^ swz(r)) << 4));
      }
      #pragma unroll
      for (int n = 0; n < 4; ++n) {
        const unsigned r = (unsigned)(wc * 64 + n * 16 + l15);
        bfv[n] = *(const f16x8*)(Bc + r * 128 + (((unsigned)(kk * 4 + l4) ^ swz(r)) << 4));
      }
      #pragma unroll
      for (int m = 0; m < 8; ++m)
        #pragma unroll
        for (int n = 0; n < 4; ++n)
          acc[m][n] = __builtin_amdgcn_mfma_f32_16x16x32_f16(afv[m], bfv[n], acc[m][n], 0, 0, 0);
    }
    __syncthreads();
    cur ^= 1;
  }
  #pragma unroll
  for (int n = 0; n < 4; ++n) {
    const int col = n0 + wc * 64 + n * 16 + l15;
    const float bz = BIAS[col];
    #pragma unroll
    for (int m = 0; m < 8; ++m) {
      const int rbase = row0 + wr * 128 + m * 16 + l4 * 4;
      #pragma unroll
      for (int r = 0; r < 4; ++r)
        OUT[(size_t)(rbase + r) * N_DIM + col] = acc[m][n][r] + bz;
    }
  }
}

extern "C" void kernel_launch(void* const* d_in, const int* in_sizes, int n_in,
                              void* d_out, int out_size, void* d_ws, size_t ws_size,
                              hipStream_t stream) {
  const float* x = nullptr; const int* qw = nullptr; const int* qz = nullptr;
  const float* s = nullptr; const float* b = nullptr;
  for (int i = 0; i < n_in; ++i) {
    switch (in_sizes[i]) {
      case M_DIM * K_DIM:   x  = (const float*)d_in[i]; break;
      case K_DIM * NPACK:   qw = (const int*)d_in[i];   break;
      case NGROUPS * NPACK: qz = (const int*)d_in[i];   break;
      case NGROUPS * N_DIM: s  = (const float*)d_in[i]; break;
      case N_DIM:           b  = (const float*)d_in[i]; break;
    }
  }
  float* out = (float*)d_out;

  const size_t xh_bytes  = (size_t)M_DIM * K_DIM * 2;          // 8 MiB
  const size_t qwr_bytes = (size_t)K8 * N_DIM * 4;             // 22.5 MiB
  dim3 grid(N_DIM / BN, M_DIM / BM);                           // 86 x 8 = 688
  const int repack_blocks = (NPACK * K8) / 256;                // 2752 exact

  if (ws_size >= xh_bytes + qwr_bytes) {
    unsigned short* xh = (unsigned short*)d_ws;
    unsigned* qwr = (unsigned*)((char*)d_ws + xh_bytes);
    conv_x<<<(M_DIM * K_DIM) / (256 * 8), 256, 0, stream>>>(x, xh);
    repack_qw<<<repack_blocks, 256, 0, stream>>>(qw, qwr);
    awq_gemm_rb<true><<<grid, dim3(256), 0, stream>>>(xh, nullptr, qwr, qz, s, b, out);
  } else if (ws_size >= qwr_bytes) {
    unsigned* qwr = (unsigned*)d_ws;
    repack_qw<<<repack_blocks, 256, 0, stream>>>(qw, qwr);
    awq_gemm_rb<false><<<grid, dim3(256), 0, stream>>>(nullptr, x, qwr, qz, s, b, out);
  } else {
    awq_gemm_fb<<<dim3(N_DIM / 256, M_DIM / 256), dim3(512), 0, stream>>>(x, qw, qz, s, b, out);
  }
}

// Round 9
// 143.850 us; speedup vs baseline: 2.3004x; 1.2446x over previous
//
#include <hip/hip_runtime.h>
#include <stdint.h>

#define M_DIM 1024
#define K_DIM 4096
#define N_DIM 11008
#define NPACK 1376
#define NGROUPS 32
#define K8 (K_DIM / 8)      // 512

#define BM 128
#define BN 128
#define BK 64
#define NT (K_DIM / BK)     // 64
#define ATILE (BM * BK)     // 8192 shorts = 16 KiB

typedef __attribute__((ext_vector_type(16))) float f32x16;
typedef __attribute__((ext_vector_type(4))) float f32x4;
typedef __attribute__((ext_vector_type(8))) _Float16 f16x8;
typedef __attribute__((ext_vector_type(2))) _Float16 h2;

static __device__ __forceinline__ unsigned swz(unsigned r) {
  return (r ^ (r >> 3)) & 7u;
}

// ---------- prepass 1: x fp32 -> fp16 (exact; x was originally fp16) ----------
__global__ __launch_bounds__(256)
void conv_x(const float* __restrict__ X, unsigned short* __restrict__ XH) {
  const size_t i = ((size_t)blockIdx.x * 256 + threadIdx.x) * 8;
  const float4 a = *(const float4*)(X + i);
  const float4 b = *(const float4*)(X + i + 4);
  uint4 o;
  o.x = __builtin_bit_cast(unsigned, __builtin_amdgcn_cvt_pkrtz(a.x, a.y));
  o.y = __builtin_bit_cast(unsigned, __builtin_amdgcn_cvt_pkrtz(a.z, a.w));
  o.z = __builtin_bit_cast(unsigned, __builtin_amdgcn_cvt_pkrtz(b.x, b.y));
  o.w = __builtin_bit_cast(unsigned, __builtin_amdgcn_cvt_pkrtz(b.z, b.w));
  *(uint4*)(XH + i) = o;
}

// ---------- prepass 2: repack qweight nibbles K-major per column ----------
// QWR[k8][n] = nibbles k = 8*k8..8*k8+7 of column n (nibble i <-> k8*8+i)
__global__ __launch_bounds__(256)
void repack_qw(const int* __restrict__ QW, unsigned* __restrict__ QWR) {
  const int idx = blockIdx.x * 256 + threadIdx.x;
  const int p  = idx % NPACK;
  const int k8 = idx / NPACK;
  unsigned a[8];
  #pragma unroll
  for (int i = 0; i < 8; ++i)
    a[i] = (unsigned)QW[(size_t)(k8 * 8 + i) * NPACK + p];
  #pragma unroll
  for (int i = 0; i < 8; i += 2) {
    unsigned t = ((a[i] >> 4) ^ a[i + 1]) & 0x0F0F0F0Fu;
    a[i + 1] ^= t;  a[i] ^= t << 4;
  }
  #pragma unroll
  for (int g = 0; g < 8; g += 4)
    #pragma unroll
    for (int i = 0; i < 2; ++i) {
      unsigned t = ((a[g + i] >> 8) ^ a[g + i + 2]) & 0x00FF00FFu;
      a[g + i + 2] ^= t;  a[g + i] ^= t << 8;
    }
  #pragma unroll
  for (int i = 0; i < 4; ++i) {
    unsigned t = ((a[i] >> 16) ^ a[i + 4]) & 0x0000FFFFu;
    a[i + 4] ^= t;  a[i] ^= t << 16;
  }
  const int REV[8] = {0, 4, 1, 5, 2, 6, 3, 7};
  #pragma unroll
  for (int j = 0; j < 8; ++j)
    QWR[(size_t)k8 * N_DIM + 8 * p + j] = a[REV[j]];
}

// ---------- main: 512 thr, 8 waves (2x4), 32x32x16 MFMA, reg-B dequant ----------
template <bool PREX>
__global__ __launch_bounds__(512, 4)
void awq_gemm32(const unsigned short* __restrict__ XH,
                const float* __restrict__ XF,
                const unsigned* __restrict__ QWR,
                const int* __restrict__ QZ,
                const float* __restrict__ S,
                const float* __restrict__ BIAS,
                float* __restrict__ OUT)
{
  __shared__ unsigned short Alds[2][ATILE];   // 2 x 16 KiB

  const int tid  = threadIdx.x;
  const int lane = tid & 63;
  const int wid  = tid >> 6;      // 0..7
  const int wrow = wid >> 2;      // 2 wave rows (64 rows each)
  const int wcol = wid & 3;       // 4 wave cols (32 cols each)
  const int l31  = lane & 31;
  const int hi   = lane >> 5;     // 0/1

  const int row0 = blockIdx.y * BM;
  const int n0   = blockIdx.x * BN;
  const int col  = n0 + wcol * 32 + l31;     // this lane's output column

  // zero-nibble shift: j = col&7, rev[j] = (j>>1)|((j&1)<<2)
  const int jz   = col & 7;
  const int sh_z = (((jz >> 1) | ((jz & 1) << 2)) << 2);

  // hoisted A LDS byte offsets: aoff[mf][ks]
  unsigned aoff[2][4];
  #pragma unroll
  for (int mf = 0; mf < 2; ++mf) {
    const unsigned r = (unsigned)(wrow * 64 + mf * 32 + l31);
    #pragma unroll
    for (int ks = 0; ks < 4; ++ks)
      aoff[mf][ks] = r * 128 + (((unsigned)(ks * 2 + hi) ^ swz(r)) << 4);
  }

  f32x16 acc[2];
  acc[0] = (f32x16)(0.f);
  acc[1] = (f32x16)(0.f);

  unsigned zz, ss;     // group constants (packed fp16)
  unsigned qn; float sn;

  auto prepLoad = [&](int grp) {
    qn = (unsigned)QZ[grp * NPACK + (col >> 3)];
    sn = S[(size_t)grp * N_DIM + col];
  };
  auto prepCalc = [&]() {
    const unsigned z = (qn >> sh_z) & 15u;
    zz = z * 0x10001u + 0x64006400u;
    ss = __builtin_bit_cast(unsigned, __builtin_amdgcn_cvt_pkrtz(sn, sn));
  };

  auto stageA = [&](unsigned short* dst, int k0) {
    if constexpr (PREX) {
      #pragma unroll
      for (int i = 0; i < 2; ++i) {
        const int gb = i * 512 + wid * 64;     // wave-uniform granule base
        const int g  = gb + lane;
        const unsigned r = (unsigned)(g >> 3), c = (unsigned)(g & 7);
        const unsigned short* gsrc =
            XH + (size_t)(row0 + r) * K_DIM + k0 + ((c ^ swz(r)) << 3);
        __builtin_amdgcn_global_load_lds(
            (const __attribute__((address_space(1))) void*)gsrc,
            (__attribute__((address_space(3))) void*)(dst + gb * 8), 16, 0, 0);
      }
    } else {
      #pragma unroll
      for (int i = 0; i < 2; ++i) {
        const int g = i * 512 + tid;
        const unsigned r = (unsigned)(g >> 3), c = (unsigned)(g & 7);
        const float* src = XF + (size_t)(row0 + r) * K_DIM + k0 + (c << 3);
        const float4 v0 = *(const float4*)src;
        const float4 v1 = *(const float4*)(src + 4);
        uint4 o;
        o.x = __builtin_bit_cast(unsigned, __builtin_amdgcn_cvt_pkrtz(v0.x, v0.y));
        o.y = __builtin_bit_cast(unsigned, __builtin_amdgcn_cvt_pkrtz(v0.z, v0.w));
        o.z = __builtin_bit_cast(unsigned, __builtin_amdgcn_cvt_pkrtz(v1.x, v1.y));
        o.w = __builtin_bit_cast(unsigned, __builtin_amdgcn_cvt_pkrtz(v1.z, v1.w));
        *(uint4*)((char*)dst + r * 128 + ((c ^ swz(r)) << 4)) = o;
      }
    }
  };

  // B: one dword per k-step: k = t*64 + ks*16 + 8*hi + i  ->  k8 = t*8 + ks*2 + hi
  auto loadB = [&](unsigned* dst, int t) {
    const unsigned* bp = QWR + (size_t)(t * 8 + hi) * N_DIM + col;
    #pragma unroll
    for (int ks = 0; ks < 4; ++ks)
      dst[ks] = bp[(size_t)(ks * 2) * N_DIM];
  };

  auto compute = [&](const unsigned short* Ab, const unsigned* breg) {
    #pragma unroll
    for (int ks = 0; ks < 4; ++ks) {
      const unsigned w = breg[ks];
      const unsigned e = w & 0x0F0F0F0Fu;
      const unsigned o = (w >> 4) & 0x0F0F0F0Fu;
      union { unsigned u[4]; f16x8 v; } bf;
      #pragma unroll
      for (int q = 0; q < 4; ++q) {
        const unsigned sel = 0x0C000C00u | (unsigned)q | ((unsigned)(4 + q) << 16);
        const unsigned hv  = __builtin_amdgcn_perm(o, e, sel) | 0x64006400u;
        const h2 wv = (__builtin_bit_cast(h2, hv) - __builtin_bit_cast(h2, zz)) *
                      __builtin_bit_cast(h2, ss);
        bf.u[q] = __builtin_bit_cast(unsigned, wv);
      }
      #pragma unroll
      for (int mf = 0; mf < 2; ++mf) {
        const f16x8 af = *(const f16x8*)((const char*)Ab + aoff[mf][ks]);
        acc[mf] = __builtin_amdgcn_mfma_f32_32x32x16_f16(af, bf.v, acc[mf], 0, 0, 0);
      }
    }
  };

  unsigned bE[4], bO[4];

  // ---------------- prologue ----------------
  prepLoad(0); prepCalc();
  stageA(&Alds[0][0], 0);
  loadB(bE, 0);
  __syncthreads();

  // ---------------- main loop: 32 iters x 2 tiles ----------------
  for (int I = 0; I < 32; ++I) {
    stageA(&Alds[1][0], (2 * I + 1) * BK);
    loadB(bO, 2 * I + 1);
    compute(&Alds[0][0], bE);
    __syncthreads();
    if (I < 31) {
      stageA(&Alds[0][0], (2 * I + 2) * BK);
      loadB(bE, 2 * I + 2);
      prepLoad(I + 1);
    }
    compute(&Alds[1][0], bO);     // group-I constants
    if (I < 31) prepCalc();
    __syncthreads();
  }

  // ---------------- epilogue ----------------
  // C/D 32x32 (m74/m101): col = lane&31, row = (reg&3) + 8*(reg>>2) + 4*(lane>>5)
  const float bz = BIAS[col];
  #pragma unroll
  for (int mf = 0; mf < 2; ++mf) {
    const int rbase = row0 + wrow * 64 + mf * 32 + 4 * hi;
    #pragma unroll
    for (int r = 0; r < 16; ++r) {
      const int row = rbase + (r & 3) + 8 * (r >> 2);
      OUT[(size_t)row * N_DIM + col] = acc[mf][r] + bz;
    }
  }
}

// ---------------- fallback (round-5 structure, fp32 x, no/small ws) ----------------
__global__ __launch_bounds__(512, 2)
void awq_gemm_fb(const float* __restrict__ XF,
                 const int* __restrict__ QW,
                 const int* __restrict__ QZ,
                 const float* __restrict__ S,
                 const float* __restrict__ BIAS,
                 float* __restrict__ OUT)
{
  __shared__ unsigned short Al[2][256 * 64];
  __shared__ unsigned short Bl[2][256 * 64];

  const int tid = threadIdx.x, lane = tid & 63, wid = tid >> 6;
  const int wr = wid >> 2, wc = wid & 3, l15 = lane & 15, l4 = lane >> 4;
  const int row0 = blockIdx.y * 256, n0 = blockIdx.x * 256, p0 = n0 >> 3;
  const int dq_p = tid & 31, dq_k = (tid >> 5) << 2;

  f32x4 acc[8][4];
  #pragma unroll
  for (int i = 0; i < 8; ++i)
    #pragma unroll
    for (int j = 0; j < 4; ++j) acc[i][j] = (f32x4){0.f, 0.f, 0.f, 0.f};

  const int SH[8] = {0, 16, 4, 20, 8, 24, 12, 28};
  unsigned zz[8], ssv[8];

  auto stageA = [&](int buf, int k0) {
    #pragma unroll
    for (int i = 0; i < 4; ++i) {
      const int g = i * 512 + tid;
      const unsigned r = (unsigned)(g >> 3), c = (unsigned)(g & 7);
      const float* src = XF + (size_t)(row0 + r) * K_DIM + k0 + (c << 3);
      const float4 v0 = *(const float4*)src;
      const float4 v1 = *(const float4*)(src + 4);
      uint4 o;
      o.x = __builtin_bit_cast(unsigned, __builtin_amdgcn_cvt_pkrtz(v0.x, v0.y));
      o.y = __builtin_bit_cast(unsigned, __builtin_amdgcn_cvt_pkrtz(v0.z, v0.w));
      o.z = __builtin_bit_cast(unsigned, __builtin_amdgcn_cvt_pkrtz(v1.x, v1.y));
      o.w = __builtin_bit_cast(unsigned, __builtin_amdgcn_cvt_pkrtz(v1.z, v1.w));
      *(uint4*)((char*)&Al[buf][0] + r * 128 + ((c ^ swz(r)) << 4)) = o;
    }
  };
  auto prepGroup = [&](int grp) {
    const unsigned qzv = (unsigned)QZ[grp * NPACK + p0 + dq_p];
    const float* sp = S + (size_t)grp * N_DIM + n0 + dq_p * 8;
    const float4 sv0 = *(const float4*)sp;
    const float4 sv1 = *(const float4*)(sp + 4);
    const float svf[8] = {sv0.x, sv0.y, sv0.z, sv0.w, sv1.x, sv1.y, sv1.z, sv1.w};
    #pragma unroll
    for (int j = 0; j < 8; ++j) {
      const unsigned z = (qzv >> SH[j]) & 15u;
      zz[j] = z * 0x10001u + 0x64006400u;
      ssv[j] = __builtin_bit_cast(unsigned, __builtin_amdgcn_cvt_pkrtz(svf[j], svf[j]));
    }
  };
  unsigned qwc[4], qwn[4];
  auto loadQW = [&](unsigned* dst, int k0) {
    #pragma unroll
    for (int i = 0; i < 4; ++i)
      dst[i] = (unsigned)QW[(size_t)(k0 + dq_k + i) * NPACK + p0 + dq_p];
  };
  auto deqB = [&](int buf, const unsigned* qw) {
    #pragma unroll
    for (int j = 0; j < 8; ++j) {
      const int sh = SH[j];
      const unsigned q01 = ((qw[0] >> sh) & 15u) | (((qw[1] >> sh) & 15u) << 16) | 0x64006400u;
      const unsigned q23 = ((qw[2] >> sh) & 15u) | (((qw[3] >> sh) & 15u) << 16) | 0x64006400u;
      const h2 w01 = (__builtin_bit_cast(h2, q01) - __builtin_bit_cast(h2, zz[j])) *
                     __builtin_bit_cast(h2, ssv[j]);
      const h2 w23 = (__builtin_bit_cast(h2, q23) - __builtin_bit_cast(h2, zz[j])) *
                     __builtin_bit_cast(h2, ssv[j]);
      uint2 wb;
      wb.x = __builtin_bit_cast(unsigned, w01);
      wb.y = __builtin_bit_cast(unsigned, w23);
      const unsigned nn = dq_p * 8 + j;
      *(uint2*)((char*)&Bl[buf][0] + nn * 128 + ((dq_k * 2) ^ (swz(nn) << 4))) = wb;
    }
  };

  stageA(0, 0); prepGroup(0); loadQW(qwc, 0); deqB(0, qwc); loadQW(qwn, BK);
  __syncthreads();
  int cur = 0;
  for (int t = 0; t < NT; ++t) {
    if (t + 1 < NT) {
      const int kn = (t + 1) * BK;
      stageA(cur ^ 1, kn);
      if (((t + 1) & 1) == 0) prepGroup((t + 1) >> 1);
      deqB(cur ^ 1, qwn);
      if (t + 2 < NT) loadQW(qwn, kn + BK);
    }
    const char* Ac = (const char*)&Al[cur][0];
    const char* Bc = (const char*)&Bl[cur][0];
    #pragma unroll
    for (int kk = 0; kk < 2; ++kk) {
      f16x8 afv[8], bfv[4];
      #pragma unroll
      for (int m = 0; m < 8; ++m) {
        const unsigned r = (unsigned)(wr * 128 + m * 16 + l15);
        afv[m] = *(const f16x8*)(Ac + r * 128 + (((unsigned)(kk * 4 + l4) ^ swz(r)) << 4));
      }
      #pragma unroll
      for (int n = 0; n < 4; ++n) {
        const unsigned r = (unsigned)(wc * 64 + n * 16 + l15);
        bfv[n] = *(const f16x8*)(Bc + r * 128 + (((unsigned)(kk * 4 + l4) ^ swz(r)) << 4));
      }
      #pragma unroll
      for (int m = 0; m < 8; ++m)
        #pragma unroll
        for (int n = 0; n < 4; ++n)
          acc[m][n] = __builtin_amdgcn_mfma_f32_16x16x32_f16(afv[m], bfv[n], acc[m][n], 0, 0, 0);
    }
    __syncthreads();
    cur ^= 1;
  }
  #pragma unroll
  for (int n = 0; n < 4; ++n) {
    const int c2 = n0 + wc * 64 + n * 16 + l15;
    const float bz = BIAS[c2];
    #pragma unroll
    for (int m = 0; m < 8; ++m) {
      const int rbase = row0 + wr * 128 + m * 16 + l4 * 4;
      #pragma unroll
      for (int r = 0; r < 4; ++r)
        OUT[(size_t)(rbase + r) * N_DIM + c2] = acc[m][n][r] + bz;
    }
  }
}

extern "C" void kernel_launch(void* const* d_in, const int* in_sizes, int n_in,
                              void* d_out, int out_size, void* d_ws, size_t ws_size,
                              hipStream_t stream) {
  const float* x = nullptr; const int* qw = nullptr; const int* qz = nullptr;
  const float* s = nullptr; const float* b = nullptr;
  for (int i = 0; i < n_in; ++i) {
    switch (in_sizes[i]) {
      case M_DIM * K_DIM:   x  = (const float*)d_in[i]; break;
      case K_DIM * NPACK:   qw = (const int*)d_in[i];   break;
      case NGROUPS * NPACK: qz = (const int*)d_in[i];   break;
      case NGROUPS * N_DIM: s  = (const float*)d_in[i]; break;
      case N_DIM:           b  = (const float*)d_in[i]; break;
    }
  }
  float* out = (float*)d_out;

  const size_t xh_bytes  = (size_t)M_DIM * K_DIM * 2;          // 8 MiB
  const size_t qwr_bytes = (size_t)K8 * N_DIM * 4;             // 22.5 MiB
  dim3 grid(N_DIM / BN, M_DIM / BM);                           // 86 x 8 = 688
  const int repack_blocks = (NPACK * K8) / 256;                // 2752 exact

  if (ws_size >= xh_bytes + qwr_bytes) {
    unsigned short* xh = (unsigned short*)d_ws;
    unsigned* qwr = (unsigned*)((char*)d_ws + xh_bytes);
    conv_x<<<(M_DIM * K_DIM) / (256 * 8), 256, 0, stream>>>(x, xh);
    repack_qw<<<repack_blocks, 256, 0, stream>>>(qw, qwr);
    awq_gemm32<true><<<grid, dim3(512), 0, stream>>>(xh, nullptr, qwr, qz, s, b, out);
  } else if (ws_size >= qwr_bytes) {
    unsigned* qwr = (unsigned*)d_ws;
    repack_qw<<<repack_blocks, 256, 0, stream>>>(qw, qwr);
    awq_gemm32<false><<<grid, dim3(512), 0, stream>>>(nullptr, x, qwr, qz, s, b, out);
  } else {
    awq_gemm_fb<<<dim3(N_DIM / 256, M_DIM / 256), dim3(512), 0, stream>>>(x, qw, qz, s, b, out);
  }
}